// Round 9
// baseline (210.626 us; speedup 1.0000x reference)
//
#include <hip/hip_runtime.h>
#include <math.h>

// Cost weights / focal params (match reference)
#define W_CLASS 1.0f
#define W_BBOX  5.0f
#define W_GIOU  2.0f
#define F_ALPHA 0.25f
#define F_EPS   1e-8f

typedef float f2 __attribute__((ext_vector_type(2)));

// v_rcp_f32 + one Newton step (bit-identical softmax denominator vs passing runs)
__device__ __forceinline__ float fast_rcp_nr(float x) {
    float r = __builtin_amdgcn_rcpf(x);
    r = fmaf(fmaf(-x, r, 1.0f), r, r);
    return r;
}

// Single fused kernel, round-7 structure:
//  Phase A: wave w computes the focal class-cost row for pred row n0+w
//           directly into LDS (identical math to the passing class kernel;
//           4x grid.x redundancy proven free in r4/r5).
//  Phase B: byte-for-byte round 7 — 4 targets/thread, LDS delta gathers,
//           regular float4 stores.
#define RPB 4   // pred rows per block == waves per block

__global__ __launch_bounds__(256)
void fused_cost_kernel(const float* __restrict__ logits,       // [N,128]
                       const float4* __restrict__ pred_boxes,  // [N,4] cxcywh
                       const float4* __restrict__ tgt_bbox,    // [T,4] cxcywh
                       const int* __restrict__ tgt_ids,        // [T]
                       float* __restrict__ out,                // [N,T]
                       int T) {
    __shared__ float dl[RPB * 128];   // 2 KB

    const int n0 = blockIdx.y * RPB;

    // ---------------- Phase A: class-cost rows -> LDS ----------------
    {
        const int w = threadIdx.x >> 6;      // wave w owns pred row n0+w
        const int l = threadIdx.x & 63;
        f2 x = ((const f2*)(logits + (size_t)(n0 + w) * 128))[l];

        float m = fmaxf(x.x, x.y);
        #pragma unroll
        for (int off = 32; off > 0; off >>= 1)
            m = fmaxf(m, __shfl_xor(m, off));

        float e0 = __expf(x.x - m);
        float e1 = __expf(x.y - m);
        float s = e0 + e1;
        #pragma unroll
        for (int off = 32; off > 0; off >>= 1)
            s += __shfl_xor(s, off);
        float inv = fast_rcp_nr(s);

        float p0 = e0 * inv, p1 = e1 * inv;
        float omp0 = 1.0f - p0, omp1 = 1.0f - p1;
        float d0 = F_ALPHA * omp0 * omp0 * (-__logf(p0 + F_EPS))
                 - (1.0f - F_ALPHA) * p0 * p0 * (-__logf(omp0 + F_EPS));
        float d1 = F_ALPHA * omp1 * omp1 * (-__logf(p1 + F_EPS))
                 - (1.0f - F_ALPHA) * p1 * p1 * (-__logf(omp1 + F_EPS));

        f2 o; o.x = d0; o.y = d1;
        ((f2*)(dl + w * 128))[l] = o;        // 8B stride: conflict-free
    }
    __syncthreads();

    // ---------------- Phase B: cost matrix (round-7 verbatim) ----------------
    const int t0 = (blockIdx.x * blockDim.x + threadIdx.x) * 4;
    if (t0 < T) {
        // 4 consecutive targets per thread (vector loads: 1x int4 + 4x float4)
        const int4 idv = *(const int4*)(tgt_ids + t0);
        const int id[4] = { idv.x, idv.y, idv.z, idv.w };

        float4 tb[4];
        float tx0[4], ty0[4], tx1[4], ty1[4], tarea[4];
        #pragma unroll
        for (int j = 0; j < 4; ++j) {
            tb[j] = tgt_bbox[t0 + j];
            tx0[j] = fmaf(-0.5f, tb[j].z, tb[j].x);
            ty0[j] = fmaf(-0.5f, tb[j].w, tb[j].y);
            tx1[j] = fmaf( 0.5f, tb[j].z, tb[j].x);
            ty1[j] = fmaf( 0.5f, tb[j].w, tb[j].y);
            tarea[j] = tb[j].z * tb[j].w;
        }

        #pragma unroll
        for (int r = 0; r < RPB; ++r) {
            const int n = n0 + r;
            const float4 pb = pred_boxes[n];   // block-uniform -> scalar load
            const float px0 = fmaf(-0.5f, pb.z, pb.x), py0 = fmaf(-0.5f, pb.w, pb.y);
            const float px1 = fmaf( 0.5f, pb.z, pb.x), py1 = fmaf( 0.5f, pb.w, pb.y);
            const float parea = pb.z * pb.w;

            float c[4];
            #pragma unroll
            for (int j = 0; j < 4; ++j) {
                const float d = dl[r * 128 + id[j]];   // ds_read, ~2-way alias: free

                float cb = fabsf(pb.x - tb[j].x) + fabsf(pb.y - tb[j].y)
                         + fabsf(pb.z - tb[j].z) + fabsf(pb.w - tb[j].w);

                // intersection raw extents (reused for enclosure via max+min=sum)
                float iwr = fminf(px1, tx1[j]) - fmaxf(px0, tx0[j]);
                float ihr = fminf(py1, ty1[j]) - fmaxf(py0, ty0[j]);
                float inter = fmaxf(iwr, 0.0f) * fmaxf(ihr, 0.0f);
                float uni = parea + tarea[j] - inter;
                float ew = (pb.z + tb[j].z) - iwr;
                float eh = (pb.w + tb[j].w) - ihr;
                float earea = ew * eh;

                // giou = inter*rcp(uni) + uni*rcp(earea) - 1
                float terms = fmaf(inter, __builtin_amdgcn_rcpf(uni),
                                   uni * __builtin_amdgcn_rcpf(earea));
                // C = 5*cb + d + 2 - 2*terms
                float cc = fmaf(W_BBOX, cb, d + 2.0f);
                c[j] = fmaf(-W_GIOU, terms, cc);
            }

            float4 o; o.x = c[0]; o.y = c[1]; o.z = c[2]; o.w = c[3];
            *(float4*)(out + (size_t)n * T + t0) = o;
        }
    }
}

extern "C" void kernel_launch(void* const* d_in, const int* in_sizes, int n_in,
                              void* d_out, int out_size, void* d_ws, size_t ws_size,
                              hipStream_t stream) {
    const float* pred_logits = (const float*)d_in[0];   // [16,900,128] f32
    const float* pred_boxes  = (const float*)d_in[1];   // [16,900,4]  f32
    const int*   tgt_ids     = (const int*)d_in[2];     // [3200] int32
    const float* tgt_bbox    = (const float*)d_in[3];   // [3200,4] f32
    float* out = (float*)d_out;
    (void)d_ws; (void)ws_size;                          // delta lives in LDS now

    const int N = in_sizes[1] / 4;   // bs*Q = 14400
    const int T = in_sizes[2];       // 3200

    // One fused dispatch: grid (4, 3600), 256 threads (4 waves = RPB rows)
    dim3 grid((T / 4 + 255) / 256, N / RPB);
    fused_cost_kernel<<<grid, 256, 0, stream>>>(
        pred_logits, (const float4*)pred_boxes, (const float4*)tgt_bbox,
        tgt_ids, out, T);
}

// Round 12
// 207.664 us; speedup vs baseline: 1.0143x; 1.0143x over previous
//
#include <hip/hip_runtime.h>
#include <math.h>

// Cost weights / focal params (match reference)
#define W_CLASS 1.0f
#define W_BBOX  5.0f
#define W_GIOU  2.0f
#define F_ALPHA 0.25f
#define F_EPS   1e-8f

typedef float f2 __attribute__((ext_vector_type(2)));

// v_rcp_f32 + one Newton step (bit-identical softmax denominator vs passing runs)
__device__ __forceinline__ float fast_rcp_nr(float x) {
    float r = __builtin_amdgcn_rcpf(x);
    r = fmaf(fmaf(-x, r, 1.0f), r, r);
    return r;
}

// Phase 1: per-row softmax over C=128 logits + focal class-cost table.
// Identical math to the round-1..7 passing versions.
__global__ __launch_bounds__(256)
void class_cost_kernel(const float* __restrict__ logits,
                       float* __restrict__ delta) {
    const int wave = threadIdx.x >> 6;
    const int lane = threadIdx.x & 63;
    const int n = blockIdx.x * 4 + wave;

    f2 x = ((const f2*)(logits + (size_t)n * 128))[lane];

    float m = fmaxf(x.x, x.y);
    #pragma unroll
    for (int off = 32; off > 0; off >>= 1)
        m = fmaxf(m, __shfl_xor(m, off));

    float e0 = __expf(x.x - m);
    float e1 = __expf(x.y - m);
    float s = e0 + e1;
    #pragma unroll
    for (int off = 32; off > 0; off >>= 1)
        s += __shfl_xor(s, off);
    float inv = fast_rcp_nr(s);

    float p0 = e0 * inv, p1 = e1 * inv;
    float omp0 = 1.0f - p0, omp1 = 1.0f - p1;
    float d0 = F_ALPHA * omp0 * omp0 * (-__logf(p0 + F_EPS))
             - (1.0f - F_ALPHA) * p0 * p0 * (-__logf(omp0 + F_EPS));
    float d1 = F_ALPHA * omp1 * omp1 * (-__logf(p1 + F_EPS))
             - (1.0f - F_ALPHA) * p1 * p1 * (-__logf(omp1 + F_EPS));

    f2 o; o.x = d0; o.y = d1;
    ((f2*)(delta + (size_t)n * 128))[lane] = o;
}

// Phase 2: round-7 structure (measured best, 207.9). Single experimental axis:
// GIoU terms via ONE v_rcp instead of two —
//   inter/uni + uni/earea = (inter*earea + uni*uni) * rcp(uni*earea)
// (round-11 bug: numerator had a spurious -uni*earea term -> output shifted +2;
//  absmax 2.0625 = 2 + 0.0625 diagnosed it exactly. Fixed: num = uni^2 + inter*earea.)
#define RPB 4   // pred rows per block == waves per block (cooperative stage)

__global__ __launch_bounds__(256)
void cost_kernel(const float4* __restrict__ pred_boxes,   // [N,4] cxcywh
                 const float4* __restrict__ tgt_bbox,     // [T,4] cxcywh
                 const int* __restrict__ tgt_ids,         // [T]
                 const float* __restrict__ delta,         // [N,128]
                 float* __restrict__ out,                 // [N,T]
                 int T) {
    __shared__ float dl[RPB * 128];   // 2 KB

    const int n0 = blockIdx.y * RPB;

    // Cooperative delta stage: wave w loads row w (64 lanes x 8B = 512B, coalesced)
    {
        const int w = threadIdx.x >> 6;
        const int l = threadIdx.x & 63;
        f2 v = ((const f2*)(delta + (size_t)(n0 + w) * 128))[l];
        ((f2*)(dl + w * 128))[l] = v;    // 8B stride: conflict-free
    }
    __syncthreads();

    const int t0 = (blockIdx.x * blockDim.x + threadIdx.x) * 4;
    if (t0 < T) {
        // 4 consecutive targets per thread (vector loads: 1x int4 + 4x float4)
        const int4 idv = *(const int4*)(tgt_ids + t0);
        const int id[4] = { idv.x, idv.y, idv.z, idv.w };

        float4 tb[4];
        float tx0[4], ty0[4], tx1[4], ty1[4], tarea[4];
        #pragma unroll
        for (int j = 0; j < 4; ++j) {
            tb[j] = tgt_bbox[t0 + j];
            tx0[j] = fmaf(-0.5f, tb[j].z, tb[j].x);
            ty0[j] = fmaf(-0.5f, tb[j].w, tb[j].y);
            tx1[j] = fmaf( 0.5f, tb[j].z, tb[j].x);
            ty1[j] = fmaf( 0.5f, tb[j].w, tb[j].y);
            tarea[j] = tb[j].z * tb[j].w;
        }

        #pragma unroll
        for (int r = 0; r < RPB; ++r) {
            const int n = n0 + r;
            const float4 pb = pred_boxes[n];   // block-uniform -> scalar load
            const float px0 = fmaf(-0.5f, pb.z, pb.x), py0 = fmaf(-0.5f, pb.w, pb.y);
            const float px1 = fmaf( 0.5f, pb.z, pb.x), py1 = fmaf( 0.5f, pb.w, pb.y);
            const float parea = pb.z * pb.w;

            float c[4];
            #pragma unroll
            for (int j = 0; j < 4; ++j) {
                const float d = dl[r * 128 + id[j]];   // ds_read, ~2-way alias: free

                float cb = fabsf(pb.x - tb[j].x) + fabsf(pb.y - tb[j].y)
                         + fabsf(pb.z - tb[j].z) + fabsf(pb.w - tb[j].w);

                // intersection raw extents (reused for enclosure via max+min=sum)
                float iwr = fminf(px1, tx1[j]) - fmaxf(px0, tx0[j]);
                float ihr = fminf(py1, ty1[j]) - fmaxf(py0, ty0[j]);
                float inter = fmaxf(iwr, 0.0f) * fmaxf(ihr, 0.0f);
                float uni = parea + tarea[j] - inter;
                float ew = (pb.z + tb[j].z) - iwr;
                float eh = (pb.w + tb[j].w) - ihr;
                float earea = ew * eh;

                // terms = inter/uni + uni/earea = (inter*earea + uni^2) * rcp(uni*earea)
                float num = fmaf(uni, uni, inter * earea);
                float terms = num * __builtin_amdgcn_rcpf(uni * earea);
                // C = 5*cb + d + 2 - 2*terms   (giou = terms - 1 folded into +2)
                float cc = fmaf(W_BBOX, cb, d + 2.0f);
                c[j] = fmaf(-W_GIOU, terms, cc);
            }

            float4 o; o.x = c[0]; o.y = c[1]; o.z = c[2]; o.w = c[3];
            *(float4*)(out + (size_t)n * T + t0) = o;
        }
    }
}

extern "C" void kernel_launch(void* const* d_in, const int* in_sizes, int n_in,
                              void* d_out, int out_size, void* d_ws, size_t ws_size,
                              hipStream_t stream) {
    const float* pred_logits = (const float*)d_in[0];   // [16,900,128] f32
    const float* pred_boxes  = (const float*)d_in[1];   // [16,900,4]  f32
    const int*   tgt_ids     = (const int*)d_in[2];     // [3200] int32
    const float* tgt_bbox    = (const float*)d_in[3];   // [3200,4] f32
    float* out = (float*)d_out;
    float* delta = (float*)d_ws;                        // [14400,128] f32 = 7.4 MB

    const int N = in_sizes[1] / 4;   // bs*Q = 14400
    const int T = in_sizes[2];       // 3200

    // Phase 1: class-cost table (one wave per row, 4 rows/block)
    class_cost_kernel<<<N / 4, 256, 0, stream>>>(pred_logits, delta);

    // Phase 2: full cost matrix, 4 targets/thread, LDS-staged delta gathers
    dim3 grid((T / 4 + 255) / 256, N / RPB);   // (4, 3600)
    cost_kernel<<<grid, 256, 0, stream>>>(
        (const float4*)pred_boxes, (const float4*)tgt_bbox, tgt_ids, delta, out, T);
}